// Round 10
// baseline (74.186 us; speedup 1.0000x reference)
//
#include <hip/hip_runtime.h>
#include <stdint.h>

typedef short v8s __attribute__((ext_vector_type(8)));
typedef float v4f __attribute__((ext_vector_type(4)));
typedef unsigned int u32;

#define CIN   320
#define COUT  320
#define HH    64
#define WW    64
#define BN    80
#define NT    10
#define XSB   25344      // one x buffer: 6 rows * 66 cols * 64B
#define WLB   15360      // one weight kh-slice: 3kw * 4cig * 80co * 16B
#define WKHB  61440      // bytes per (t,kh) slice in w_deq2: 3*4*320*16

__device__ __forceinline__ float hf8_decode_f(int b) {
    int e = (b >> 3) & 15;
    int m = b & 7;
    float v = ldexpf((float)(e ? (8 + m) : m), e ? (e - 17) : -16);
    return ((b >> 7) & 1) ? -v : v;
}

__device__ __forceinline__ u32 cvt_pk_bf16(float lo, float hi) {
    u32 r;
    asm("v_cvt_pk_bf16_f32 %0, %1, %2" : "=v"(r) : "v"(lo), "v"(hi));
    return r;
}

__device__ __forceinline__ void gload16(const void* g, void* l) {
    __builtin_amdgcn_global_load_lds(
        (const __attribute__((address_space(1))) u32*)(uintptr_t)g,
        (__attribute__((address_space(3))) u32*)(uintptr_t)l, 16, 0, 0);
}

// ============ merged pre-pass (R7-proven): dequant (blocks 0..3599) + convert ============
// w_deq2: [t(10)][kh(3)][kw(3)][cig(4)][co(320)][e(8)] bf16
// x_t   : [n(8)][cig(10)][hp(66)][w(64)][ci(32)] bf16, hp halo rows zeroed
__global__ __launch_bounds__(256) void prepass_kernel(const int* __restrict__ w_bits,
                                                      const int* __restrict__ b_bits,
                                                      const float* __restrict__ x,
                                                      unsigned short* __restrict__ w_deq2,
                                                      float* __restrict__ b_deq,
                                                      unsigned short* __restrict__ x_t) {
    __shared__ __align__(16) unsigned short lt[32 * 64];
    const int tid = threadIdx.x;
    if (blockIdx.x < 3600) {
        int o  = blockIdx.x * 256 + tid;
        int e  = o & 7;
        int c2 = o >> 3;
        int co = c2 % COUT;
        int c3 = c2 / COUT;
        int cig = c3 & 3;
        int c4 = c3 >> 2;
        int kw = c4 % 3;
        int c5 = c4 / 3;
        int kh = c5 % 3;
        int t  = c5 / 3;
        int ci = t * 32 + cig * 8 + e;
        float v = hf8_decode_f(w_bits[(co * CIN + ci) * 9 + kh * 3 + kw] & 0xFF);
        w_deq2[o] = (unsigned short)(__float_as_uint(v) >> 16);
        if (o < COUT) b_deq[o] = hf8_decode_f(b_bits[o] & 0xFF);
        return;
    }
    const int b  = blockIdx.x - 3600;    // (n*10 + cig)*66 + hp
    const int hp = b % 66;
    const int nc = b / 66;
    char* outp = (char*)x_t + (size_t)b * 4096;
    if (hp == 0 || hp == 65) {
        *(int4*)(outp + tid * 16) = make_int4(0, 0, 0, 0);
        return;
    }
    const int h = hp - 1;
    {
        int ci = tid >> 3, wg = tid & 7;
        const float* src = x + ((size_t)nc * 32 + ci) * (HH * WW) + h * WW + wg * 8;
        float4 a = *(const float4*)src;
        float4 c = *(const float4*)(src + 4);
        u32 d0 = cvt_pk_bf16(a.x, a.y);
        u32 d1 = cvt_pk_bf16(a.z, a.w);
        u32 d2 = cvt_pk_bf16(c.x, c.y);
        u32 d3 = cvt_pk_bf16(c.z, c.w);
        *(int4*)&lt[ci * 64 + wg * 8] = make_int4(d0, d1, d2, d3);
    }
    __syncthreads();
    if (tid < 128) {
        int w2 = tid & 31, o = tid >> 5;
        u32 A[4], B[4];
        #pragma unroll
        for (int j = 0; j < 4; ++j) {
            int p = o * 4 + j;
            u32 de = *(const u32*)&lt[(2 * p) * 64 + w2 * 2];
            u32 dq = *(const u32*)&lt[(2 * p + 1) * 64 + w2 * 2];
            A[j] = __builtin_amdgcn_perm(dq, de, 0x05040100u);
            B[j] = __builtin_amdgcn_perm(dq, de, 0x07060302u);
        }
        *(int4*)(outp + (2 * w2) * 64 + o * 16)     = make_int4(A[0], A[1], A[2], A[3]);
        *(int4*)(outp + (2 * w2 + 1) * 64 + o * 16) = make_int4(B[0], B[1], B[2], B[3]);
    }
}

// ===== conv: 128 thr / 2 waves, mr=8 x nr=5 per wave, R7 barrier protocol =====
__global__ __launch_bounds__(128, 1) void conv_phase_kernel(
        const unsigned short* __restrict__ x_t,
        const unsigned short* __restrict__ w_deq2,
        const float* __restrict__ b_deq,
        float* __restrict__ out) {
    __shared__ __align__(16) unsigned short xs[2 * XSB / 2];   // 50,688 B
    __shared__ __align__(16) unsigned short wl[2 * WLB / 2];   // 30,720 B (total 81,408)

    const int tid  = threadIdx.x;
    const int bid  = blockIdx.x;
    const int cob  = bid >> 7;        // same-x blocks (d=128, 128%8==0) share an XCD
    const int mb   = bid & 127;       // 8 img x 16 rowgroups
    const int n    = mb >> 4;
    const int h0   = (mb & 15) << 2;  // 4 output rows per block
    const int wave = tid >> 6;        // wave owns output rows h0+2*wave .. +1
    const int lane = tid & 63;
    const int lhi  = lane >> 4;
    const int llo  = lane & 15;

    // zero halo cols (xs col 0 and 65) of both buffers, once
    for (int i = tid; i < 384; i += 128) {
        int buf = i / 192;
        int r   = (i - buf * 192) >> 5;
        int rem = i & 31;
        int side = rem >> 4, e = rem & 15;
        *(u32*)((char*)xs + buf * XSB + r * 4224 + side * 4160 + e * 4) = 0;
    }

    // weight gload offsets: chunk c = k*128 + tid (c < 960), q = c/80 (kw*4+cig)
    int woffW[8];
    #pragma unroll
    for (int k = 0; k < 8; ++k) {
        int c = k * 128 + tid;
        int q = c / BN;
        int co = c - q * BN;
        woffW[k] = (q * COUT + cob * BN + co) << 4;
    }

    v4f acc[2][4][5];
    #pragma unroll
    for (int r = 0; r < 2; ++r)
        #pragma unroll
        for (int wc = 0; wc < 4; ++wc)
            #pragma unroll
            for (int j = 0; j < 5; ++j)
                acc[r][wc][j] = (v4f){0.f, 0.f, 0.f, 0.f};

    const char* xt_base = (const char*)x_t + ((size_t)(n * NT) * 66 + h0) * 4096;

    auto issueW = [&](int t_, int kh_, int wb) {
        const char* base = (const char*)w_deq2 + (size_t)(t_ * 3 + kh_) * WKHB;
        char* dst = (char*)wl + wb * WLB + tid * 16;
        #pragma unroll
        for (int k = 0; k < 8; ++k) {
            if (k * 128 + tid < 960)
                gload16(base + woffW[k], dst + k * 2048);
        }
    };
    auto issueX = [&](int t_, int xb) {
        const char* src = xt_base + (size_t)t_ * (66 * 4096);
        char* dstb = (char*)xs + xb * XSB;
        #pragma unroll
        for (int k = 0; k < 12; ++k) {
            int c = k * 128 + tid;          // 0..1535
            int j = c >> 8;                 // xs row 0..5 (wave-uniform)
            int u = c & 255;                // 16B chunk within row
            gload16(src + j * 4096 + u * 16, dstb + j * 4224 + 64 + u * 16);
        }
    };
    auto computeKh = [&](int kh, int xb, int wb) {
        const char* xp = (const char*)xs + xb * XSB + (2 * wave + kh) * 4224;
        const unsigned short* wp = wl + wb * (WLB / 2);
        __builtin_amdgcn_s_setprio(1);
        #pragma unroll
        for (int kw = 0; kw < 3; ++kw) {
            v8s bfr[5];
            #pragma unroll
            for (int nr = 0; nr < 5; ++nr)
                bfr[nr] = *(const v8s*)&wp[((kw * 4 + lhi) * BN + nr * 16 + llo) * 8];
            #pragma unroll
            for (int r = 0; r < 2; ++r)
                #pragma unroll
                for (int wc = 0; wc < 4; ++wc) {
                    v8s afr = *(const v8s*)(xp + r * 4224 + (wc * 16 + llo + kw) * 64 + lhi * 16);
                    #pragma unroll
                    for (int nr = 0; nr < 5; ++nr)
                        acc[r][wc][nr] = __builtin_amdgcn_mfma_f32_16x16x32_bf16(
                            afr, bfr[nr], acc[r][wc][nr], 0, 0, 0);
                }
        }
        __builtin_amdgcn_s_setprio(0);
    };

    // prologue: stage tile 0
    issueW(0, 0, 0);
    issueX(0, 0);

    for (int t = 0; t < NT; ++t) {
        const int p = t & 1;
        // phase kh0: reads wl[p], xs[p]
        __syncthreads();                        // A: w(t,kh0)+x(t) drained
        issueW(t, 1, p ^ 1);
        computeKh(0, p, p);
        // phase kh1: reads wl[p^1]
        __syncthreads();                        // B
        issueW(t, 2, p);
        computeKh(1, p, p ^ 1);
        // phase kh2: reads wl[p]
        __syncthreads();                        // C
        if (t + 1 < NT) { issueW(t + 1, 0, p ^ 1); issueX(t + 1, p ^ 1); }
        computeKh(2, p, p);
    }

    // epilogue: bias + float4 stores
    #pragma unroll
    for (int nr = 0; nr < 5; ++nr) {
        int co = cob * BN + nr * 16 + llo;      // D col = lane&15
        float bias = b_deq[co];
        #pragma unroll
        for (int r = 0; r < 2; ++r) {
            int h = h0 + 2 * wave + r;
            float* op = out + ((size_t)(n * COUT + co) * HH + h) * WW + lhi * 4;
            #pragma unroll
            for (int wc = 0; wc < 4; ++wc) {
                float4 o;
                o.x = acc[r][wc][nr][0] + bias;
                o.y = acc[r][wc][nr][1] + bias;
                o.z = acc[r][wc][nr][2] + bias;
                o.w = acc[r][wc][nr][3] + bias;
                *(float4*)(op + wc * 16) = o;   // D row = lhi*4 + j within 16-col frag
            }
        }
    }
}

extern "C" void kernel_launch(void* const* d_in, const int* in_sizes, int n_in,
                              void* d_out, int out_size, void* d_ws, size_t ws_size,
                              hipStream_t stream) {
    const float* x      = (const float*)d_in[0];
    const int*   w_bits = (const int*)d_in[1];
    const int*   b_bits = (const int*)d_in[2];
    float*       out    = (float*)d_out;

    unsigned short* w_deq2 = (unsigned short*)d_ws;                 // 1,843,200 B
    float*          b_deq  = (float*)((char*)d_ws + 1843200);
    unsigned short* x_t    = (unsigned short*)((char*)d_ws + (2u << 20)); // 21.6 MB

    prepass_kernel<<<8880, 256, 0, stream>>>(w_bits, b_bits, x, w_deq2, b_deq, x_t);
    // 4 cob x (8 img x 16 rowgroups) = 512 workgroups = 2 blocks/CU, zero tail
    conv_phase_kernel<<<512, 128, 0, stream>>>(x_t, w_deq2, b_deq, out);
}

// Round 11
// 68.535 us; speedup vs baseline: 1.0825x; 1.0825x over previous
//
#include <hip/hip_runtime.h>
#include <stdint.h>

typedef short v8s __attribute__((ext_vector_type(8)));
typedef float v4f __attribute__((ext_vector_type(4)));
typedef unsigned int u32;

#define CIN    320
#define COUT   320
#define HH     64
#define WW     64
#define BN     80
#define NT     10
#define XSB    25344     // one x buffer: 6 rows * 66 cols * 64B
#define WLBUF  5120      // one weight slice buffer: 4 cig * 80 co * 16B
#define WSLICE 20480     // bytes per (t,kh,kw) slice in w_deq3: 4*320*16

__device__ __forceinline__ float hf8_decode_f(int b) {
    int e = (b >> 3) & 15;
    int m = b & 7;
    float v = ldexpf((float)(e ? (8 + m) : m), e ? (e - 17) : -16);
    return ((b >> 7) & 1) ? -v : v;
}

__device__ __forceinline__ u32 cvt_pk_bf16(float lo, float hi) {
    u32 r;
    asm("v_cvt_pk_bf16_f32 %0, %1, %2" : "=v"(r) : "v"(lo), "v"(hi));
    return r;
}

__device__ __forceinline__ void gload16(const void* g, void* l) {
    __builtin_amdgcn_global_load_lds(
        (const __attribute__((address_space(1))) u32*)(uintptr_t)g,
        (__attribute__((address_space(3))) u32*)(uintptr_t)l, 16, 0, 0);
}

// ============ merged pre-pass: dequant (blocks 0..3599) + x convert ============
// w_deq3: [g(90)=t*9+kh*3+kw][cig(4)][co(320)][e(8)] bf16
// x_t   : [n(8)][cig(10)][hp(66)][w(64)][ci(32)] bf16, hp halo rows zeroed
__global__ __launch_bounds__(256) void prepass_kernel(const int* __restrict__ w_bits,
                                                      const int* __restrict__ b_bits,
                                                      const float* __restrict__ x,
                                                      unsigned short* __restrict__ w_deq3,
                                                      float* __restrict__ b_deq,
                                                      unsigned short* __restrict__ x_t) {
    __shared__ __align__(16) unsigned short lt[32 * 64];
    const int tid = threadIdx.x;
    if (blockIdx.x < 3600) {
        int o  = blockIdx.x * 256 + tid;      // 921600 ushorts
        int e  = o & 7;
        int c2 = o >> 3;
        int co = c2 % COUT;
        int c3 = c2 / COUT;
        int cig = c3 & 3;
        int g  = c3 >> 2;                     // 0..89
        int kw = g % 3;
        int kh = (g / 3) % 3;
        int t  = g / 9;
        int ci = t * 32 + cig * 8 + e;
        float v = hf8_decode_f(w_bits[(co * CIN + ci) * 9 + kh * 3 + kw] & 0xFF);
        w_deq3[o] = (unsigned short)(__float_as_uint(v) >> 16);
        if (o < COUT) b_deq[o] = hf8_decode_f(b_bits[o] & 0xFF);
        return;
    }
    const int b  = blockIdx.x - 3600;    // (n*10 + cig)*66 + hp
    const int hp = b % 66;
    const int nc = b / 66;
    char* outp = (char*)x_t + (size_t)b * 4096;
    if (hp == 0 || hp == 65) {
        *(int4*)(outp + tid * 16) = make_int4(0, 0, 0, 0);
        return;
    }
    const int h = hp - 1;
    {
        int ci = tid >> 3, wg = tid & 7;
        const float* src = x + ((size_t)nc * 32 + ci) * (HH * WW) + h * WW + wg * 8;
        float4 a = *(const float4*)src;
        float4 c = *(const float4*)(src + 4);
        u32 d0 = cvt_pk_bf16(a.x, a.y);
        u32 d1 = cvt_pk_bf16(a.z, a.w);
        u32 d2 = cvt_pk_bf16(c.x, c.y);
        u32 d3 = cvt_pk_bf16(c.z, c.w);
        *(int4*)&lt[ci * 64 + wg * 8] = make_int4(d0, d1, d2, d3);
    }
    __syncthreads();
    if (tid < 128) {
        int w2 = tid & 31, o = tid >> 5;
        u32 A[4], B[4];
        #pragma unroll
        for (int j = 0; j < 4; ++j) {
            int p = o * 4 + j;
            u32 de = *(const u32*)&lt[(2 * p) * 64 + w2 * 2];
            u32 dq = *(const u32*)&lt[(2 * p + 1) * 64 + w2 * 2];
            A[j] = __builtin_amdgcn_perm(dq, de, 0x05040100u);
            B[j] = __builtin_amdgcn_perm(dq, de, 0x07060302u);
        }
        *(int4*)(outp + (2 * w2) * 64 + o * 16)     = make_int4(A[0], A[1], A[2], A[3]);
        *(int4*)(outp + (2 * w2 + 1) * 64 + o * 16) = make_int4(B[0], B[1], B[2], B[3]);
    }
}

// ===== conv: 256 thr / 4 waves, 2 blocks/CU, 9-phase counted-vmcnt pipeline =====
__global__ __launch_bounds__(256, 2) void conv_t4_kernel(
        const unsigned short* __restrict__ x_t,
        const unsigned short* __restrict__ w_deq3,
        const float* __restrict__ b_deq,
        float* __restrict__ out) {
    __shared__ __align__(16) unsigned short xs[2 * XSB / 2];   // 50,688 B
    __shared__ __align__(16) unsigned short wl[3 * WLBUF / 2]; // 15,360 B (total 66,048)

    const int tid  = threadIdx.x;
    const int bid  = blockIdx.x;
    const int cob  = bid >> 7;        // 4 cout blocks
    const int mb   = bid & 127;       // 8 img x 16 rowgroups
    const int n    = mb >> 4;
    const int h0   = (mb & 15) << 2;  // 4 output rows per block
    const int wave = tid >> 6;        // wave owns output row h0+wave
    const int lane = tid & 63;
    const int lhi  = lane >> 4;
    const int llo  = lane & 15;

    // zero halo cols (xs col 0 and 65) of both buffers, once
    for (int i = tid; i < 384; i += 256) {
        int buf = i / 192;
        int r   = (i - buf * 192) >> 5;
        int rem = i & 31;
        int side = rem >> 4, e = rem & 15;
        *(u32*)((char*)xs + buf * XSB + r * 4224 + side * 4160 + e * 4) = 0;
    }

    // weight gload per-lane offsets: chunk cm = ((wave*2+k)*64 % 320) + lane
    int woffW[2], wdst[2];
    #pragma unroll
    for (int k = 0; k < 2; ++k) {
        int jj  = wave * 2 + k;             // 0..7
        int cmb = (jj * 64) % 320;
        int cm  = cmb + lane;               // <= 319
        int cig = cm / BN;
        int co  = cm - cig * BN;
        woffW[k] = (cig * COUT + cob * BN + co) << 4;
        wdst[k]  = cmb << 4;
    }

    v4f acc[4][5];
    #pragma unroll
    for (int i = 0; i < 4; ++i)
        #pragma unroll
        for (int j = 0; j < 5; ++j)
            acc[i][j] = (v4f){0.f, 0.f, 0.f, 0.f};

    const char* xt_lane = (const char*)x_t + ((size_t)(n * NT) * 66 + h0) * 4096 + lane * 16;

    auto issueW = [&](int g, int buf) {     // slice g -> wl[buf]; 2 instrs/wave
        const char* base = (const char*)w_deq3 + (size_t)g * WSLICE;
        char* dst = (char*)wl + buf * WLBUF;
        gload16(base + woffW[0], dst + wdst[0]);
        gload16(base + woffW[1], dst + wdst[1]);
    };
    auto issueX1 = [&](int tt, int xb, int m) {  // one instr/wave, m = 0..5
        int id = wave * 6 + m;
        int j = id >> 2, k = id & 3;
        gload16(xt_lane + (size_t)tt * (66 * 4096) + j * 4096 + k * 1024,
                (char*)xs + xb * XSB + j * 4224 + 64 + k * 1024);
    };
    auto phaseCompute = [&](int kh, int kw, int xb, int buf) {
        const unsigned short* wp = (const unsigned short*)((const char*)wl + buf * WLBUF);
        const char* xp = (const char*)xs + xb * XSB + (wave + kh) * 4224;
        v8s bfr[5];
        #pragma unroll
        for (int nr = 0; nr < 5; ++nr)
            bfr[nr] = *(const v8s*)&wp[(lhi * BN + nr * 16 + llo) * 8];
        __builtin_amdgcn_s_setprio(1);
        #pragma unroll
        for (int mr = 0; mr < 4; ++mr) {
            v8s afr = *(const v8s*)(xp + (mr * 16 + llo + kw) * 64 + lhi * 16);
            #pragma unroll
            for (int nr = 0; nr < 5; ++nr)
                acc[mr][nr] = __builtin_amdgcn_mfma_f32_16x16x32_bf16(
                    afr, bfr[nr], acc[mr][nr], 0, 0, 0);
        }
        __builtin_amdgcn_s_setprio(0);
    };

    // prologue: FIFO = [w(0) x2, X(0) x6, w(1) x2] -> vmcnt(2) at first barrier
    issueW(0, 0);
    #pragma unroll
    for (int m = 0; m < 6; ++m) issueX1(0, 0, m);
    issueW(1, 1);
    asm volatile("s_waitcnt lgkmcnt(0)" ::: "memory");   // halo ds_writes flushed

// phase macro: counted-vmcnt barrier, issue slice i+2 + one X chunk, compute (kh,kw)
#define PHASE(I, NSTR)                                                        \
    {                                                                         \
        if (t == NT - 1) { asm volatile("s_waitcnt vmcnt(0)" ::: "memory"); } \
        else             { asm volatile("s_waitcnt vmcnt(" NSTR ")" ::: "memory"); } \
        __builtin_amdgcn_s_barrier();                                         \
        __builtin_amdgcn_sched_barrier(0);                                    \
        int g2 = t * 9 + (I) + 2;                                             \
        if (g2 <= 89) issueW(g2, ((I) + 2) % 3);                              \
        if ((I) <= 5 && t + 1 < NT) issueX1(t + 1, p ^ 1, (I));               \
        phaseCompute((I) / 3, (I) % 3, p, (I) % 3);                           \
    }

    for (int t = 0; t < NT; ++t) {
        const int p = t & 1;
        PHASE(0, "2")
        PHASE(1, "3")
        PHASE(2, "4")
        PHASE(3, "4")
        PHASE(4, "4")
        PHASE(5, "4")
        PHASE(6, "4")
        PHASE(7, "3")
        PHASE(8, "2")
    }
#undef PHASE

    // epilogue: bias + float4 stores (D col = lane&15 -> co; row = lhi*4+j -> w)
    const int h = h0 + wave;
    #pragma unroll
    for (int nr = 0; nr < 5; ++nr) {
        int co = cob * BN + nr * 16 + llo;
        float bias = b_deq[co];
        float* op = out + ((size_t)(n * COUT + co) * HH + h) * WW;
        #pragma unroll
        for (int mr = 0; mr < 4; ++mr) {
            int wc = mr * 16 + lhi * 4;
            float4 o;
            o.x = acc[mr][nr][0] + bias;
            o.y = acc[mr][nr][1] + bias;
            o.z = acc[mr][nr][2] + bias;
            o.w = acc[mr][nr][3] + bias;
            *(float4*)(op + wc) = o;
        }
    }
}

extern "C" void kernel_launch(void* const* d_in, const int* in_sizes, int n_in,
                              void* d_out, int out_size, void* d_ws, size_t ws_size,
                              hipStream_t stream) {
    const float* x      = (const float*)d_in[0];
    const int*   w_bits = (const int*)d_in[1];
    const int*   b_bits = (const int*)d_in[2];
    float*       out    = (float*)d_out;

    unsigned short* w_deq3 = (unsigned short*)d_ws;                      // 1,843,200 B
    float*          b_deq  = (float*)((char*)d_ws + 1843200);
    unsigned short* x_t    = (unsigned short*)((char*)d_ws + (2u << 20)); // 21.6 MB

    prepass_kernel<<<8880, 256, 0, stream>>>(w_bits, b_bits, x, w_deq3, b_deq, x_t);
    // 4 cob x (8 img x 16 rowgroups) = 512 workgroups = 2 blocks/CU, 8 waves/CU
    conv_t4_kernel<<<512, 256, 0, stream>>>(x_t, w_deq3, b_deq, out);
}